// Round 1
// 25214.767 us; speedup vs baseline: 1.2157x; 1.2157x over previous
//
#include <hip/hip_runtime.h>
#include <cstdint>
#include <cstddef>

// FBRNN: T=16384, F=2048, H=16, A=64, L=6, G=3H=48.
// gi0 GEMM precomputed in permuted layout [t][k*4+gate].
// Scan: 1 block x 512 threads, zero barriers in the step loop; LDS flag sync.
// Role map (SIMD = wv%4):
//   SIMD0: w0 = GRU chain        | w4 = gi0 chunk streamer (near-idle)
//   SIMD1: w1 = combine i=0 (6r) | w5 = combine i=4 (2r)
//   SIMD2: w2 = combine i=1 (5r) | w6 = fc head + out store
//   SIMD3: w3 = combine i=2 (4r) | w7 = combine i=3 (3r)
// R9 (this round):
//  - exp2-prescaled weights: r/z rows x(-log2e), n rows x(2log2e), Wa/ba
//    x(2log2e), va x(log2e) -> every transcendental is a bare v_exp_f32.
//  - all divides -> v_rcp_f32 (__builtin_amdgcn_rcpf); no IEEE div sequences.
//  - flag stores RELAXED + compile barrier (LDS ops are in-order per wave;
//    removes the s_waitcnt lgkmcnt(0) drain the RELEASE stores forced).
//  - chain layer: ns computed directly at qg2 (readlane 4k+2, no qbcast<2>
//    on the path); gh+bih folded into dot init; (1-z), z*h precomputed in
//    tanh's shadow; cached cntC poll; gh/h loads issued before housekeeping.

#define TT 16384
#define FF 2048
#define HH 16
#define LL 6
#define GG 48
#define CHUNK 64
#define LOG2E 1.44269504088896340736f

__device__ float g_gi0p[(TT + CHUNK) * 64];

__device__ __forceinline__ float exp2_(float x) { return __builtin_amdgcn_exp2f(x); }
__device__ __forceinline__ float rcp_(float x) { return __builtin_amdgcn_rcpf(x); }
// sigmoid(x) with input pre-scaled s = -log2e*x
__device__ __forceinline__ float sig_n(float s) { return rcp_(1.f + exp2_(s)); }
// tanh(x) with input pre-scaled s = 2*log2e*x
__device__ __forceinline__ float tanh_p(float s) { return fmaf(-2.f, rcp_(exp2_(s) + 1.f), 1.f); }

#define MEMBAR() __asm__ __volatile__("" ::: "memory")

__device__ __forceinline__ float rdlane(float v, int l) {
  union { float f; int i; } a, b;
  a.f = v; b.i = __builtin_amdgcn_readlane(a.i, l); return b.f;
}
template <int CTRL>
__device__ __forceinline__ float dppf(float v) {
  union { float f; int i; } a, b;
  a.f = v; b.i = __builtin_amdgcn_mov_dpp(a.i, CTRL, 0xF, 0xF, true); return b.f;
}
template <int Q>
__device__ __forceinline__ float qbcast(float v) { return dppf<Q | (Q << 2) | (Q << 4) | (Q << 6)>(v); }

__device__ __forceinline__ float rowsum16(float v) {
  v += dppf<0xB1>(v);   // xor1
  v += dppf<0x4E>(v);   // xor2
  v += dppf<0x141>(v);  // row_half_mirror
  v += dppf<0x140>(v);  // row_mirror
  return v;
}
__device__ __forceinline__ float dot16r(const float (&w)[16], const float (&h)[16]) {
  float s0 = w[0] * h[0], s1 = w[1] * h[1], s2 = w[2] * h[2], s3 = w[3] * h[3];
#pragma unroll
  for (int k = 4; k < 16; k += 4) {
    s0 = fmaf(w[k], h[k], s0);       s1 = fmaf(w[k + 1], h[k + 1], s1);
    s2 = fmaf(w[k + 2], h[k + 2], s2); s3 = fmaf(w[k + 3], h[k + 3], s3);
  }
  return (s0 + s1) + (s2 + s3);
}
__device__ __forceinline__ float dot16i(const float (&w)[16], const float (&h)[16], float init) {
  float s0 = fmaf(w[0], h[0], init), s1 = w[1] * h[1], s2 = w[2] * h[2], s3 = w[3] * h[3];
#pragma unroll
  for (int k = 4; k < 16; k += 4) {
    s0 = fmaf(w[k], h[k], s0);       s1 = fmaf(w[k + 1], h[k + 1], s1);
    s2 = fmaf(w[k + 2], h[k + 2], s2); s3 = fmaf(w[k + 3], h[k + 3], s3);
  }
  return (s0 + s1) + (s2 + s3);
}

__device__ __forceinline__ void pollGE(int* f, int target) {
  while (__hip_atomic_load(f, __ATOMIC_ACQUIRE, __HIP_MEMORY_SCOPE_WORKGROUP) < target) {}
}
// relaxed flag store: LDS ds ops are in-order per wave, so the preceding data
// writes complete before this does; MEMBAR() at call site pins compile order.
__device__ __forceinline__ void sigRel(int* f, int v) {
  __hip_atomic_store(f, v, __ATOMIC_RELAXED, __HIP_MEMORY_SCOPE_WORKGROUP);
}

// ---------------- Phase 1: gi0 GEMM (permuted + gate-prescaled output) ----------------
__global__ __launch_bounds__(256) void gi0_gemm(const float* __restrict__ X,
                                                const float* __restrict__ W,
                                                const float* __restrict__ bias) {
  __shared__ float xs[64][132];
  __shared__ float ws[48][132];
  const int tid = threadIdx.x;
  const int t0 = blockIdx.x * 64;
  const int tg = tid & 15;
  const int tt = tid >> 4;
  float acc[4][3];
#pragma unroll
  for (int u = 0; u < 4; ++u)
#pragma unroll
    for (int v = 0; v < 3; ++v) acc[u][v] = 0.f;

  for (int k0 = 0; k0 < FF; k0 += 128) {
#pragma unroll
    for (int i = 0; i < 32; ++i) {
      int e = tid + 256 * i; int r = e >> 7, c = e & 127;
      xs[r][c] = X[(size_t)(t0 + r) * FF + k0 + c];
    }
#pragma unroll
    for (int i = 0; i < 24; ++i) {
      int e = tid + 256 * i; int r = e >> 7, c = e & 127;
      ws[r][c] = W[(size_t)r * FF + k0 + c];
    }
    __syncthreads();
#pragma unroll 8
    for (int c = 0; c < 128; ++c) {
      float x0 = xs[tt][c], x1 = xs[tt + 16][c], x2 = xs[tt + 32][c], x3 = xs[tt + 48][c];
      float w0 = ws[tg][c], w1 = ws[tg + 16][c], w2 = ws[tg + 32][c];
      acc[0][0] += x0 * w0; acc[0][1] += x0 * w1; acc[0][2] += x0 * w2;
      acc[1][0] += x1 * w0; acc[1][1] += x1 * w1; acc[1][2] += x1 * w2;
      acc[2][0] += x2 * w0; acc[2][1] += x2 * w1; acc[2][2] += x2 * w2;
      acc[3][0] += x3 * w0; acc[3][1] += x3 * w1; acc[3][2] += x3 * w2;
    }
    __syncthreads();
  }
  const float gsc3[3] = {-LOG2E, -LOG2E, 2.f * LOG2E};  // r, z, n
#pragma unroll
  for (int u = 0; u < 4; ++u)
#pragma unroll
    for (int v = 0; v < 3; ++v)
      g_gi0p[(size_t)(t0 + tt + 16 * u) * 64 + tg * 4 + v] =
          (acc[u][v] + bias[tg + 16 * v]) * gsc3[v];
}

// ---------------- Phase 2: barrier-free sequential scan ----------------
__global__ __launch_bounds__(512, 1) void fbrnn_scan(
    const float* __restrict__ h0,
    const float* __restrict__ Whh0, const float* __restrict__ bhh0,
    const float* __restrict__ Wih, const float* __restrict__ Whh,
    const float* __restrict__ bih, const float* __restrict__ bhh,
    const float* __restrict__ Wa, const float* __restrict__ ba,
    const float* __restrict__ va,
    const float* __restrict__ fc1w, const float* __restrict__ fc1b,
    const float* __restrict__ fc2w, const float* __restrict__ fc2b,
    float* __restrict__ out) {
  __shared__ __align__(16) float nsS[2][LL * HH];     // ns, buf = t&1 (unscaled)
  __shared__ __align__(16) float hS[2][5 * HH];       // h rows 0..4 (unscaled)
  __shared__ __align__(16) float ghS[2][5 * 64];      // gh rows 0..4 (gate-prescaled)
  __shared__ __align__(16) float nsOut[256 * HH];     // ns5 ring for fc (w6)
  __shared__ __align__(16) float chunkS[2][CHUNK * 64];
  __shared__ int flagNs;      // chain: t*8 + l + 1 after ns_l visible
  __shared__ int cntC;        // combine waves: +1 each per step (5t+5 after step t)
  __shared__ int flagChunk;   // streamer: c+1 after chunk c staged
  __shared__ int flagOut;     // w6: t+1 after out[t] stored

  const int tid = threadIdx.x;
  const int wv = tid >> 6;
  const int lane = tid & 63;
  const int qg = lane & 3;
  const int kk = lane >> 2;
  const int k16 = lane & 15;
  const int gate = (qg < 3 ? qg : 2);
  const int G = gate * 16 + kk;               // gate-major row index
  const float gsc = (gate == 2) ? 2.f * LOG2E : -LOG2E;  // per-gate exp2 prescale

  // role map: chain=w0, streamer=w4, fc=w6, combine rows {w1:0,w2:1,w3:2,w7:3,w5:4}
  const bool isChain = (wv == 0);
  const bool isStream = (wv == 4);
  const bool isFc = (wv == 6);
  const bool isComb = !isChain && !isStream && !isFc;
  const int iw = (wv == 1) ? 0 : (wv == 2) ? 1 : (wv == 3) ? 2 : (wv == 7) ? 3 : 4;

  // ---- per-role register weights (prescaled at load) ----
  float WBih[5][16], bihR[5];           // chain (scaled by gsc)
  float WB5[16];  float bhh5R = 0.f;    // chain: Whh layer-5 row (scaled)
  float WaR[16], WhR[16];               // combine (WaR x 2log2e, WhR x gsc)
  float baR = 0.f, vaR = 0.f, bhhR = 0.f;
  float fc1R[16];                       // fc (unscaled)
  float fb1 = 0.f, fw2 = 0.f, fb2 = 0.f;

  if (isChain) {
#pragma unroll
    for (int l = 0; l < 5; ++l) {
#pragma unroll
      for (int k = 0; k < 16; ++k) WBih[l][k] = Wih[((l * GG) + G) * 16 + k] * gsc;
      bihR[l] = bih[l * GG + G] * gsc;
    }
#pragma unroll
    for (int k = 0; k < 16; ++k) WB5[k] = Whh[(4 * GG + G) * 16 + k] * gsc;
    bhh5R = bhh[4 * GG + G] * gsc;
  } else if (isComb) {
#pragma unroll
    for (int k = 0; k < 16; ++k) WaR[k] = Wa[(iw * 16 + k) * 64 + lane] * (2.f * LOG2E);
    baR = ba[iw * 64 + lane] * (2.f * LOG2E);
    vaR = va[iw * 64 + lane] * LOG2E;
    const float* wsrc = (iw == 0) ? (Whh0 + G * 16) : (Whh + ((iw - 1) * GG + G) * 16);
#pragma unroll
    for (int k = 0; k < 16; ++k) WhR[k] = wsrc[k] * gsc;
    bhhR = ((iw == 0) ? bhh0[G] : bhh[(iw - 1) * GG + G]) * gsc;
  } else if (isFc) {
    const int m = lane & 31;
#pragma unroll
    for (int k = 0; k < 16; ++k) fc1R[k] = fc1w[m * 16 + k];
    fb1 = fc1b[m]; fw2 = fc2w[m]; fb2 = fc2b[0];
  }

  if (tid == 0) { flagNs = 0; cntC = 0; flagChunk = 1; flagOut = 0; }

  float hv5 = 0.f, gh5reg = 0.f;  // chain registers
  if (isChain) {
    hv5 = h0[5 * 16 + kk];
    float hr[16];
#pragma unroll
    for (int k = 0; k < 16; ++k) hr[k] = h0[5 * 16 + k];
    gh5reg = dot16i(WB5, hr, bhh5R);
  } else if (isComb) {
    if (lane < 16) hS[1][iw * 16 + k16] = h0[iw * 16 + k16];
    float hr[16];
#pragma unroll
    for (int k = 0; k < 16; ++k) hr[k] = h0[iw * 16 + k];
    ghS[1][iw * 64 + lane] = dot16i(WhR, hr, bhhR);
  } else if (isStream) {
    const float4* src = (const float4*)g_gi0p;
    float4* dst = (float4*)(&chunkS[0][0]);
#pragma unroll
    for (int q = 0; q < 16; ++q) dst[q * 64 + lane] = src[q * 64 + lane];
  }
  __syncthreads();  // the only barrier

  // ================= streamer (w4, SIMD0 partner of the chain) =================
  if (isStream) {
#pragma unroll 1
    for (int c = 1; c < 256; ++c) {
      if (c >= 2) pollGE(&flagNs, ((c - 1) * 64 - 1) * 8 + 1);
      const float4* src = (const float4*)(g_gi0p + ((size_t)c << 12));
      float4* dst = (float4*)(&chunkS[c & 1][0]);
#pragma unroll
      for (int q = 0; q < 16; ++q) dst[q * 64 + lane] = src[q * 64 + lane];
      MEMBAR();
      sigRel(&flagChunk, c + 1);
    }
    return;
  }

  // ================= fc head + output store (w6) =================
  if (isFc) {
    int fcc = 0;
#pragma unroll 1
    for (int t = 0; t < TT; ++t) {
      const int need = t * 8 + 6;
      if (fcc < need) {
        do {
          fcc = __hip_atomic_load(&flagNs, __ATOMIC_ACQUIRE, __HIP_MEMORY_SCOPE_WORKGROUP);
        } while (fcc < need);
      }
      const float4* np = (const float4*)(nsOut + (t & 255) * 16);
      float4 a0 = np[0], a1 = np[1], a2 = np[2], a3 = np[3];
      float nr[16] = {a0.x, a0.y, a0.z, a0.w, a1.x, a1.y, a1.z, a1.w,
                      a2.x, a2.y, a2.z, a2.w, a3.x, a3.y, a3.z, a3.w};
      float y = dot16i(fc1R, nr, fb1);
      float p = rowsum16(y * fw2);
      float o = rdlane(p, 0) + rdlane(p, 16) + fb2;
      if (lane == 0) out[t] = o;
      MEMBAR();
      sigRel(&flagOut, t + 1);
    }
    return;
  }

  // ================= combine row iw (w1,w2,w3,w7,w5) =================
  if (isComb) {
    int fcache = 0;  // flagNs is monotonic: cache it across polls
#pragma unroll 1
    for (int t = 0; t < TT; ++t) {
      const int nb = t & 1;
      float S = 0.f, ha = 0.f, Pa = 0.f;
      // rows iw..5: fully processed inline; rows <5 sit in the chain's shadow,
      // so only row 5's block is on the critical path.
#pragma unroll
      for (int j = 0; j < 6; ++j) {
        if (j >= iw) {
          const int need = t * 8 + j + 1;
          if (fcache < need) {
            do {
              fcache = __hip_atomic_load(&flagNs, __ATOMIC_ACQUIRE, __HIP_MEMORY_SCOPE_WORKGROUP);
            } while (fcache < need);
          }
          const float4* np = (const float4*)(&nsS[nb][j * 16]);
          float4 a0 = np[0], a1 = np[1], a2 = np[2], a3 = np[3];
          float nr[16] = {a0.x, a0.y, a0.z, a0.w, a1.x, a1.y, a1.z, a1.w,
                          a2.x, a2.y, a2.z, a2.w, a3.x, a3.y, a3.z, a3.w};
          const float nsv = nsS[nb][j * 16 + k16];
          float u = dot16i(WaR, nr, baR);       // 2log2e * (ba + Wa.nr)
          float pe = vaR * tanh_p(u);           // log2e * va * tanh
          float P = dot16r(WhR, nr);            // prescaled gh contribution
          float r = rowsum16(pe);
          float e = (rdlane(r, 0) + rdlane(r, 16)) + (rdlane(r, 32) + rdlane(r, 48));
          // softmax without max subtraction (|e| <~ 5 given 0.1-scaled weights)
          float w = exp2_(e);                   // = exp(energy), va prescaled
          S += w; ha = fmaf(w, nsv, ha); Pa = fmaf(w, P, Pa);
        }
      }
      const float inv = rcp_(S);
      if (lane < 16) hS[nb][iw * 16 + k16] = ha * inv;
      ghS[nb][iw * 64 + lane] = fmaf(Pa, inv, bhhR);
      MEMBAR();
      if (lane == 0)
        __hip_atomic_fetch_add(&cntC, 1, __ATOMIC_RELAXED, __HIP_MEMORY_SCOPE_WORKGROUP);
    }
    return;
  }

  // ================= GRU chain (w0) =================
  float gnext = chunkS[0][lane];
  float ns_sg[16];
  int ccache = 0;  // cntC is monotonic
#pragma unroll 1
  for (int t = 0; t < TT; ++t) {
    const int rb = (t + 1) & 1;  // combine(t-1) output buf
    const int wb = t & 1;        // ns buf this step

    // all 5 combine rows of step t-1 done -> issue gh/h loads immediately
    const int cneed = 5 * t;
    if (ccache < cneed) {
      do {
        ccache = __hip_atomic_load(&cntC, __ATOMIC_ACQUIRE, __HIP_MEMORY_SCOPE_WORKGROUP);
      } while (ccache < cneed);
    }
    float ghv[6], hv[6];
#pragma unroll
    for (int l = 0; l < 5; ++l) { ghv[l] = ghS[rb][l * 64 + lane]; hv[l] = hS[rb][l * 16 + kk]; }
    ghv[5] = gh5reg; hv[5] = hv5;

    // housekeeping while the gh/h loads are in flight
    if ((t & 63) == 63) {
      const int cn = (t + 1) >> 6;
      if (cn < 256) pollGE(&flagChunk, cn + 1);
    }
    if ((t & 63) == 32) pollGE(&flagOut, t - 64);
    const float gpre = chunkS[((t + 1) >> 6) & 1][((t + 1) & 63) * 64 + lane];

    float ghb[6];
#pragma unroll
    for (int l = 1; l < 6; ++l) ghb[l] = ghv[l] + bihR[l - 1];

    float gi0v = gnext;
    float ns = 0.f;
#pragma unroll
    for (int l = 0; l < 6; ++l) {
      const float gh_g = ghv[l];
      const float s = (l == 0) ? (gi0v + gh_g) : dot16i(WBih[l - 1], ns_sg, ghb[l]);
      const float sg = sig_n(s);                   // r at qg=0, z at qg=1
      const float smg = s - gh_g;                  // scaled i_n at qg=2
      const float sr = qbcast<0>(sg);
      const float sz = qbcast<1>(sg);
      const float a = sz * hv[l];                  // ready during tanh latency
      const float b = 1.f - sz;
      const float tq = tanh_p(fmaf(sr, gh_g, smg)); // n at qg=2
      ns = fmaf(tq, b, a);                         // valid at qg=2 lanes
      if (qg == 2) {
        nsS[wb][l * 16 + kk] = ns;
        if (l == 5) nsOut[(t & 255) * 16 + kk] = ns;
      }
      MEMBAR();
      // l=5's flag is latency-critical for the combine tails: release it
      // BEFORE the readlane broadcast (chain's post-release work has slack).
      if (l == 5 && lane == 0) sigRel(&flagNs, t * 8 + 6);
#pragma unroll
      for (int k = 0; k < 16; ++k) ns_sg[k] = rdlane(ns, 4 * k + 2);
      if (l < 5 && lane == 0) sigRel(&flagNs, t * 8 + l + 1);
    }
    hv5 = qbcast<2>(ns);                           // quad-uniform ns5, off-path
    gh5reg = dot16i(WB5, ns_sg, bhh5R);
    gnext = gpre;
  }
}

extern "C" void kernel_launch(void* const* d_in, const int* in_sizes, int n_in,
                              void* d_out, int out_size, void* d_ws, size_t ws_size,
                              hipStream_t stream) {
  const float* batch = (const float*)d_in[0];
  const float* h0    = (const float*)d_in[1];
  const float* Wih0  = (const float*)d_in[2];
  const float* Whh0  = (const float*)d_in[3];
  const float* bih0  = (const float*)d_in[4];
  const float* bhh0  = (const float*)d_in[5];
  const float* Wih   = (const float*)d_in[6];
  const float* Whh   = (const float*)d_in[7];
  const float* bih   = (const float*)d_in[8];
  const float* bhh   = (const float*)d_in[9];
  const float* Wa    = (const float*)d_in[10];
  const float* ba    = (const float*)d_in[11];
  const float* va    = (const float*)d_in[12];
  const float* fc1w  = (const float*)d_in[13];
  const float* fc1b  = (const float*)d_in[14];
  const float* fc2w  = (const float*)d_in[15];
  const float* fc2b  = (const float*)d_in[16];
  float* out = (float*)d_out;
  (void)in_sizes; (void)n_in; (void)out_size; (void)d_ws; (void)ws_size;

  gi0_gemm<<<TT / 64, 256, 0, stream>>>(batch, Wih0, bih0);
  fbrnn_scan<<<1, 512, 0, stream>>>(h0, Whh0, bhh0, Wih, Whh, bih, bhh,
                                    Wa, ba, va, fc1w, fc1b, fc2w, fc2b, out);
}

// Round 2
// 24989.369 us; speedup vs baseline: 1.2267x; 1.0090x over previous
//
#include <hip/hip_runtime.h>
#include <cstdint>
#include <cstddef>

// FBRNN: T=16384, F=2048, H=16, A=64, L=6, G=3H=48.
// gi0 GEMM precomputed in permuted layout [t][k*4+gate].
// Scan: 1 block x 512 threads, zero barriers in the step loop; LDS flag sync.
// Role map (SIMD = wv%4):
//   SIMD0: w0 = GRU chain          | w4 = gi0 chunk streamer (near-idle)
//   SIMD1: w1 = row0 tail (j3,4,5) | w5 = row1 helper (j1,2) + row4 tail
//   SIMD2: w2 = row1 tail (j3,4,5) | w6 = row0 helper (j0,1,2) + fc head
//   SIMD3: w3 = row2 tail (j3,4,5) | w7 = row2 helper (j2) + row3 tail
// R10: combine load rebalanced (max 3 early blocks/wave; was 6 on w1) via
// partial softmax accumulators merged at the tail; gen-packed handoffs:
//  - combine->chain: per-lane float4 record {gh, h, gen, pad}, single
//    ds_write_b128; the chain's poll IS the data read (one LDS round trip).
//  - chain->combine ns5: gen5 word read (acquire) first, data reads in the
//    same poll iteration (same-wave LDS order => gen fresh => data fresh).
// nsv accumulated at index kk so ha*inv lands in chain layout for free.

#define TT 16384
#define FF 2048
#define HH 16
#define LL 6
#define GG 48
#define CHUNK 64
#define LOG2E 1.44269504088896340736f

__device__ float g_gi0p[(TT + CHUNK) * 64];

__device__ __forceinline__ float exp2_(float x) { return __builtin_amdgcn_exp2f(x); }
__device__ __forceinline__ float rcp_(float x) { return __builtin_amdgcn_rcpf(x); }
// sigmoid(x) with input pre-scaled s = -log2e*x
__device__ __forceinline__ float sig_n(float s) { return rcp_(1.f + exp2_(s)); }
// tanh(x) with input pre-scaled s = 2*log2e*x
__device__ __forceinline__ float tanh_p(float s) { return fmaf(-2.f, rcp_(exp2_(s) + 1.f), 1.f); }

#define MEMBAR() __asm__ __volatile__("" ::: "memory")

__device__ __forceinline__ float rdlane(float v, int l) {
  union { float f; int i; } a, b;
  a.f = v; b.i = __builtin_amdgcn_readlane(a.i, l); return b.f;
}
template <int CTRL>
__device__ __forceinline__ float dppf(float v) {
  union { float f; int i; } a, b;
  a.f = v; b.i = __builtin_amdgcn_mov_dpp(a.i, CTRL, 0xF, 0xF, true); return b.f;
}
template <int Q>
__device__ __forceinline__ float qbcast(float v) { return dppf<Q | (Q << 2) | (Q << 4) | (Q << 6)>(v); }

__device__ __forceinline__ float rowsum16(float v) {
  v += dppf<0xB1>(v);   // xor1
  v += dppf<0x4E>(v);   // xor2
  v += dppf<0x141>(v);  // row_half_mirror
  v += dppf<0x140>(v);  // row_mirror
  return v;
}
__device__ __forceinline__ float dot16r(const float (&w)[16], const float (&h)[16]) {
  float s0 = w[0] * h[0], s1 = w[1] * h[1], s2 = w[2] * h[2], s3 = w[3] * h[3];
#pragma unroll
  for (int k = 4; k < 16; k += 4) {
    s0 = fmaf(w[k], h[k], s0);       s1 = fmaf(w[k + 1], h[k + 1], s1);
    s2 = fmaf(w[k + 2], h[k + 2], s2); s3 = fmaf(w[k + 3], h[k + 3], s3);
  }
  return (s0 + s1) + (s2 + s3);
}
__device__ __forceinline__ float dot16i(const float (&w)[16], const float (&h)[16], float init) {
  float s0 = fmaf(w[0], h[0], init), s1 = w[1] * h[1], s2 = w[2] * h[2], s3 = w[3] * h[3];
#pragma unroll
  for (int k = 4; k < 16; k += 4) {
    s0 = fmaf(w[k], h[k], s0);       s1 = fmaf(w[k + 1], h[k + 1], s1);
    s2 = fmaf(w[k + 2], h[k + 2], s2); s3 = fmaf(w[k + 3], h[k + 3], s3);
  }
  return (s0 + s1) + (s2 + s3);
}

__device__ __forceinline__ int ldAcq(int* f) {
  return __hip_atomic_load(f, __ATOMIC_ACQUIRE, __HIP_MEMORY_SCOPE_WORKGROUP);
}
__device__ __forceinline__ void pollGE(int* f, int target) {
  while (ldAcq(f) < target) {}
}
__device__ __forceinline__ void waitFlag(int* f, int& cache, int need) {
  if (cache < need) { do { cache = ldAcq(f); } while (cache < need); }
}
// relaxed flag store: LDS ds ops are in-order per wave; MEMBAR() pins compile order.
__device__ __forceinline__ void sigRel(int* f, int v) {
  __hip_atomic_store(f, v, __ATOMIC_RELAXED, __HIP_MEMORY_SCOPE_WORKGROUP);
}

// one softmax term: energies over 64 attention lanes, P = Wh.nr per G-lane.
__device__ __forceinline__ void combBlock(const float4 A0, const float4 A1, const float4 A2,
                                          const float4 A3, float nsv,
                                          const float (&Wa)[16], float ba, float va,
                                          const float (&Wh)[16],
                                          float& S, float& ha, float& Pa) {
  float nr[16] = {A0.x, A0.y, A0.z, A0.w, A1.x, A1.y, A1.z, A1.w,
                  A2.x, A2.y, A2.z, A2.w, A3.x, A3.y, A3.z, A3.w};
  float u = dot16i(Wa, nr, ba);        // 2log2e * (ba + Wa.nr)
  float P = dot16r(Wh, nr);            // prescaled gh contribution (off u-path)
  float pe = va * tanh_p(u);           // log2e * va * tanh
  float r = rowsum16(pe);
  float e = (rdlane(r, 0) + rdlane(r, 16)) + (rdlane(r, 32) + rdlane(r, 48));
  float w = exp2_(e);                  // = exp(energy), va prescaled
  S += w; ha = fmaf(w, nsv, ha); Pa = fmaf(w, P, Pa);
}

// ---------------- Phase 1: gi0 GEMM (permuted + gate-prescaled output) ----------------
__global__ __launch_bounds__(256) void gi0_gemm(const float* __restrict__ X,
                                                const float* __restrict__ W,
                                                const float* __restrict__ bias) {
  __shared__ float xs[64][132];
  __shared__ float ws[48][132];
  const int tid = threadIdx.x;
  const int t0 = blockIdx.x * 64;
  const int tg = tid & 15;
  const int tt = tid >> 4;
  float acc[4][3];
#pragma unroll
  for (int u = 0; u < 4; ++u)
#pragma unroll
    for (int v = 0; v < 3; ++v) acc[u][v] = 0.f;

  for (int k0 = 0; k0 < FF; k0 += 128) {
#pragma unroll
    for (int i = 0; i < 32; ++i) {
      int e = tid + 256 * i; int r = e >> 7, c = e & 127;
      xs[r][c] = X[(size_t)(t0 + r) * FF + k0 + c];
    }
#pragma unroll
    for (int i = 0; i < 24; ++i) {
      int e = tid + 256 * i; int r = e >> 7, c = e & 127;
      ws[r][c] = W[(size_t)r * FF + k0 + c];
    }
    __syncthreads();
#pragma unroll 8
    for (int c = 0; c < 128; ++c) {
      float x0 = xs[tt][c], x1 = xs[tt + 16][c], x2 = xs[tt + 32][c], x3 = xs[tt + 48][c];
      float w0 = ws[tg][c], w1 = ws[tg + 16][c], w2 = ws[tg + 32][c];
      acc[0][0] += x0 * w0; acc[0][1] += x0 * w1; acc[0][2] += x0 * w2;
      acc[1][0] += x1 * w0; acc[1][1] += x1 * w1; acc[1][2] += x1 * w2;
      acc[2][0] += x2 * w0; acc[2][1] += x2 * w1; acc[2][2] += x2 * w2;
      acc[3][0] += x3 * w0; acc[3][1] += x3 * w1; acc[3][2] += x3 * w2;
    }
    __syncthreads();
  }
  const float gsc3[3] = {-LOG2E, -LOG2E, 2.f * LOG2E};  // r, z, n
#pragma unroll
  for (int u = 0; u < 4; ++u)
#pragma unroll
    for (int v = 0; v < 3; ++v)
      g_gi0p[(size_t)(t0 + tt + 16 * u) * 64 + tg * 4 + v] =
          (acc[u][v] + bias[tg + 16 * v]) * gsc3[v];
}

// ---------------- Phase 2: barrier-free sequential scan ----------------
__global__ __launch_bounds__(512, 1) void fbrnn_scan(
    const float* __restrict__ h0,
    const float* __restrict__ Whh0, const float* __restrict__ bhh0,
    const float* __restrict__ Wih, const float* __restrict__ Whh,
    const float* __restrict__ bih, const float* __restrict__ bhh,
    const float* __restrict__ Wa, const float* __restrict__ ba,
    const float* __restrict__ va,
    const float* __restrict__ fc1w, const float* __restrict__ fc1b,
    const float* __restrict__ fc2w, const float* __restrict__ fc2b,
    float* __restrict__ out) {
  __shared__ __align__(16) float nsS[2][LL * HH];     // ns, buf = t&1 (unscaled)
  __shared__ __align__(16) float4 recS[5 * 64];       // {gh, h, genbits, pad} rows 0..4
  __shared__ __align__(16) float4 partS[3 * 64];      // {S, ha, Pa, genbits} partials
  __shared__ __align__(16) float nsOut[256 * HH];     // ns5 ring for fc (w6)
  __shared__ __align__(16) float chunkS[2][CHUNK * 64];
  __shared__ int flagNs;      // chain: t*8 + l + 1 after ns_l visible
  __shared__ int flagChunk;   // streamer: c+1 after chunk c staged
  __shared__ int flagOut;     // w6: t+1 after out[t] stored
  __shared__ int gen5[2];     // chain: t+1 after ns5 of step t stored in nsS[t&1]

  const int tid = threadIdx.x;
  const int wv = tid >> 6;
  const int lane = tid & 63;
  const int qg = lane & 3;
  const int kk = lane >> 2;
  const int gate = (qg < 3 ? qg : 2);
  const int G = gate * 16 + kk;               // gate-major row index
  const float gsc = (gate == 2) ? 2.f * LOG2E : -LOG2E;  // per-gate exp2 prescale

  const bool isChain = (wv == 0);
  const bool isStream = (wv == 4);
  const bool isFc = (wv == 6);
  const bool isComb = !isChain && !isStream && !isFc;
  // tail (primary) row per combine wave; helper row for partial producers
  const int pRow = (wv == 1) ? 0 : (wv == 2) ? 1 : (wv == 3) ? 2 : (wv == 7) ? 3 : 4;
  const int hRow = (wv == 5) ? 1 : (wv == 7) ? 2 : (wv == 6) ? 0 : -1;

  // ---- per-role register weights (prescaled at load) ----
  float WBih[5][16], bihR[5];           // chain (scaled by gsc)
  float WB5[16];  float bhh5R = 0.f;    // chain: Whh layer-5 row (scaled)
  float WaP[16], WhP[16];               // combine primary row
  float baP = 0.f, vaP = 0.f, bhhP = 0.f;
  float WaH[16], WhH[16];               // combine helper row (w5/w6/w7)
  float baH = 0.f, vaH = 0.f;
  float fc1R[16];                       // fc (unscaled)
  float fb1 = 0.f, fw2 = 0.f, fb2 = 0.f;

  if (isChain) {
#pragma unroll
    for (int l = 0; l < 5; ++l) {
#pragma unroll
      for (int k = 0; k < 16; ++k) WBih[l][k] = Wih[((l * GG) + G) * 16 + k] * gsc;
      bihR[l] = bih[l * GG + G] * gsc;
    }
#pragma unroll
    for (int k = 0; k < 16; ++k) WB5[k] = Whh[(4 * GG + G) * 16 + k] * gsc;
    bhh5R = bhh[4 * GG + G] * gsc;
  }
  if (isComb) {
#pragma unroll
    for (int k = 0; k < 16; ++k) WaP[k] = Wa[(pRow * 16 + k) * 64 + lane] * (2.f * LOG2E);
    baP = ba[pRow * 64 + lane] * (2.f * LOG2E);
    vaP = va[pRow * 64 + lane] * LOG2E;
    const float* ws = (pRow == 0) ? (Whh0 + G * 16) : (Whh + ((pRow - 1) * GG + G) * 16);
#pragma unroll
    for (int k = 0; k < 16; ++k) WhP[k] = ws[k] * gsc;
    bhhP = ((pRow == 0) ? bhh0[G] : bhh[(pRow - 1) * GG + G]) * gsc;
  }
  if (hRow >= 0) {
#pragma unroll
    for (int k = 0; k < 16; ++k) WaH[k] = Wa[(hRow * 16 + k) * 64 + lane] * (2.f * LOG2E);
    baH = ba[hRow * 64 + lane] * (2.f * LOG2E);
    vaH = va[hRow * 64 + lane] * LOG2E;
    const float* ws = (hRow == 0) ? (Whh0 + G * 16) : (Whh + ((hRow - 1) * GG + G) * 16);
#pragma unroll
    for (int k = 0; k < 16; ++k) WhH[k] = ws[k] * gsc;
  }
  if (isFc) {
    const int m = lane & 31;
#pragma unroll
    for (int k = 0; k < 16; ++k) fc1R[k] = fc1w[m * 16 + k];
    fb1 = fc1b[m]; fw2 = fc2w[m]; fb2 = fc2b[0];
  }

  if (tid == 0) { flagNs = 0; flagChunk = 1; flagOut = 0; gen5[0] = 0; gen5[1] = 0; }

  float hv5 = 0.f, gh5reg = 0.f;  // chain registers
  if (isChain) {
    hv5 = h0[5 * 16 + kk];
    float hr[16];
#pragma unroll
    for (int k = 0; k < 16; ++k) hr[k] = h0[5 * 16 + k];
    gh5reg = dot16i(WB5, hr, bhh5R);
  } else if (isComb) {
    // init rec row pRow: gh from h0, h = h0, gen = 0
    float hr[16];
#pragma unroll
    for (int k = 0; k < 16; ++k) hr[k] = h0[pRow * 16 + k];
    float4 rr;
    rr.x = dot16i(WhP, hr, bhhP);
    rr.y = h0[pRow * 16 + kk];
    rr.z = __int_as_float(0);
    rr.w = 0.f;
    recS[pRow * 64 + lane] = rr;
  } else if (isStream) {
    const float4* src = (const float4*)g_gi0p;
    float4* dst = (float4*)(&chunkS[0][0]);
#pragma unroll
    for (int q = 0; q < 16; ++q) dst[q * 64 + lane] = src[q * 64 + lane];
  }
  if (wv == 6) partS[0 * 64 + lane] = make_float4(0.f, 0.f, 0.f, __int_as_float(0));
  if (wv == 5) partS[1 * 64 + lane] = make_float4(0.f, 0.f, 0.f, __int_as_float(0));
  if (wv == 7) partS[2 * 64 + lane] = make_float4(0.f, 0.f, 0.f, __int_as_float(0));
  __syncthreads();  // the only barrier

// early combine block: wait flag, read nsS row J, accumulate one term
#define EBLOCK(J, WaX, baX, vaX, WhX, Sx, hax, Pax) do {                          \
    waitFlag(&flagNs, fcache, t * 8 + (J) + 1);                                   \
    const float4* np_ = (const float4*)&nsS[nb][(J) * 16];                        \
    float4 A0_ = np_[0], A1_ = np_[1], A2_ = np_[2], A3_ = np_[3];                \
    float nsv_ = nsS[nb][(J) * 16 + kk];                                          \
    combBlock(A0_, A1_, A2_, A3_, nsv_, WaX, baX, vaX, WhX, Sx, hax, Pax);        \
  } while (0)

  // ================= streamer (w4, SIMD0 partner of the chain) =================
  if (isStream) {
#pragma unroll 1
    for (int c = 1; c < 256; ++c) {
      if (c >= 2) pollGE(&flagNs, ((c - 1) * 64 - 1) * 8 + 1);
      const float4* src = (const float4*)(g_gi0p + ((size_t)c << 12));
      float4* dst = (float4*)(&chunkS[c & 1][0]);
#pragma unroll
      for (int q = 0; q < 16; ++q) dst[q * 64 + lane] = src[q * 64 + lane];
      MEMBAR();
      sigRel(&flagChunk, c + 1);
    }
    return;
  }

  // ================= w6: row0 helper (j0,j1,j2) + fc head =================
  if (isFc) {
    int fcache = 0;
#pragma unroll 1
    for (int t = 0; t < TT; ++t) {
      const int nb = t & 1;
      float Sh = 0.f, hah = 0.f, Pah = 0.f;
      EBLOCK(0, WaH, baH, vaH, WhH, Sh, hah, Pah);
      EBLOCK(1, WaH, baH, vaH, WhH, Sh, hah, Pah);
      EBLOCK(2, WaH, baH, vaH, WhH, Sh, hah, Pah);
      partS[0 * 64 + lane] = make_float4(Sh, hah, Pah, __int_as_float(t + 1));
      // fc tail
      waitFlag(&flagNs, fcache, t * 8 + 6);
      const float4* np = (const float4*)(nsOut + (t & 255) * 16);
      float4 a0 = np[0], a1 = np[1], a2 = np[2], a3 = np[3];
      float nr[16] = {a0.x, a0.y, a0.z, a0.w, a1.x, a1.y, a1.z, a1.w,
                      a2.x, a2.y, a2.z, a2.w, a3.x, a3.y, a3.z, a3.w};
      float y = dot16i(fc1R, nr, fb1);
      float p = rowsum16(y * fw2);
      float o = rdlane(p, 0) + rdlane(p, 16) + fb2;
      if (lane == 0) out[t] = o;
      MEMBAR();
      sigRel(&flagOut, t + 1);
    }
    return;
  }

  // ================= combine waves =================
  if (isComb) {
    int fcache = 0;
    if (wv == 5) {
      // row1 helper (j1,j2) -> partial1; row4 tail (j4,j5)
#pragma unroll 1
      for (int t = 0; t < TT; ++t) {
        const int nb = t & 1;
        const int tgt = t + 1;
        float Sh = 0.f, hah = 0.f, Pah = 0.f;
        EBLOCK(1, WaH, baH, vaH, WhH, Sh, hah, Pah);
        EBLOCK(2, WaH, baH, vaH, WhH, Sh, hah, Pah);
        partS[1 * 64 + lane] = make_float4(Sh, hah, Pah, __int_as_float(tgt));
        float S = 0.f, ha = 0.f, Pa = 0.f;
        EBLOCK(4, WaP, baP, vaP, WhP, S, ha, Pa);
        float4 A0, A1, A2, A3; float nsv5;
        for (;;) {
          int g5 = ldAcq(&gen5[nb]);
          MEMBAR();
          const float4* np = (const float4*)&nsS[nb][5 * 16];
          A0 = np[0]; A1 = np[1]; A2 = np[2]; A3 = np[3];
          nsv5 = nsS[nb][5 * 16 + kk];
          MEMBAR();
          if (g5 >= tgt) break;
        }
        combBlock(A0, A1, A2, A3, nsv5, WaP, baP, vaP, WhP, S, ha, Pa);
        const float inv = rcp_(S);
        float4 rr; rr.x = fmaf(Pa, inv, bhhP); rr.y = ha * inv;
        rr.z = __int_as_float(tgt); rr.w = 0.f;
        recS[4 * 64 + lane] = rr;
      }
    } else if (wv == 7) {
      // row2 helper (j2) -> partial2; row3 tail (j3,j4,j5)
#pragma unroll 1
      for (int t = 0; t < TT; ++t) {
        const int nb = t & 1;
        const int tgt = t + 1;
        float Sh = 0.f, hah = 0.f, Pah = 0.f;
        EBLOCK(2, WaH, baH, vaH, WhH, Sh, hah, Pah);
        partS[2 * 64 + lane] = make_float4(Sh, hah, Pah, __int_as_float(tgt));
        float S = 0.f, ha = 0.f, Pa = 0.f;
        EBLOCK(3, WaP, baP, vaP, WhP, S, ha, Pa);
        EBLOCK(4, WaP, baP, vaP, WhP, S, ha, Pa);
        float4 A0, A1, A2, A3; float nsv5;
        for (;;) {
          int g5 = ldAcq(&gen5[nb]);
          MEMBAR();
          const float4* np = (const float4*)&nsS[nb][5 * 16];
          A0 = np[0]; A1 = np[1]; A2 = np[2]; A3 = np[3];
          nsv5 = nsS[nb][5 * 16 + kk];
          MEMBAR();
          if (g5 >= tgt) break;
        }
        combBlock(A0, A1, A2, A3, nsv5, WaP, baP, vaP, WhP, S, ha, Pa);
        const float inv = rcp_(S);
        float4 rr; rr.x = fmaf(Pa, inv, bhhP); rr.y = ha * inv;
        rr.z = __int_as_float(tgt); rr.w = 0.f;
        recS[3 * 64 + lane] = rr;
      }
    } else {
      // w1/w2/w3: rows 0/1/2 tails (j3,j4,j5) + merge partial[pRow]
#pragma unroll 1
      for (int t = 0; t < TT; ++t) {
        const int nb = t & 1;
        const int tgt = t + 1;
        float S = 0.f, ha = 0.f, Pa = 0.f;
        EBLOCK(3, WaP, baP, vaP, WhP, S, ha, Pa);
        EBLOCK(4, WaP, baP, vaP, WhP, S, ha, Pa);
        float4 A0, A1, A2, A3, pp; float nsv5;
        for (;;) {
          int g5 = ldAcq(&gen5[nb]);
          MEMBAR();
          const float4* np = (const float4*)&nsS[nb][5 * 16];
          A0 = np[0]; A1 = np[1]; A2 = np[2]; A3 = np[3];
          nsv5 = nsS[nb][5 * 16 + kk];
          pp = partS[pRow * 64 + lane];
          MEMBAR();
          int pok = __all(__float_as_int(pp.w) >= tgt);
          if ((g5 >= tgt) & pok) break;
        }
        combBlock(A0, A1, A2, A3, nsv5, WaP, baP, vaP, WhP, S, ha, Pa);
        S += pp.x; ha += pp.y; Pa += pp.z;
        const float inv = rcp_(S);
        float4 rr; rr.x = fmaf(Pa, inv, bhhP); rr.y = ha * inv;
        rr.z = __int_as_float(tgt); rr.w = 0.f;
        recS[pRow * 64 + lane] = rr;
      }
    }
    return;
  }

  // ================= GRU chain (w0) =================
  float gnext = chunkS[0][lane];
  float ns_sg[16];
#pragma unroll 1
  for (int t = 0; t < TT; ++t) {
    const int wb = t & 1;        // ns buf this step

    // rec poll IS the combine(t-1) data read: all rows fresh when gen >= t
    float4 r0, r1, r2, r3, r4;
    for (;;) {
      MEMBAR();
      r0 = recS[0 * 64 + lane]; r1 = recS[1 * 64 + lane]; r2 = recS[2 * 64 + lane];
      r3 = recS[3 * 64 + lane]; r4 = recS[4 * 64 + lane];
      MEMBAR();
      int c = (__float_as_int(r0.z) >= t) & (__float_as_int(r1.z) >= t) &
              (__float_as_int(r2.z) >= t) & (__float_as_int(r3.z) >= t) &
              (__float_as_int(r4.z) >= t);
      if (__all(c)) break;
    }
    float ghv[6], hv[6];
    ghv[0] = r0.x; hv[0] = r0.y; ghv[1] = r1.x; hv[1] = r1.y;
    ghv[2] = r2.x; hv[2] = r2.y; ghv[3] = r3.x; hv[3] = r3.y;
    ghv[4] = r4.x; hv[4] = r4.y;
    ghv[5] = gh5reg; hv[5] = hv5;

    // housekeeping (slack region)
    if ((t & 63) == 63) {
      const int cn = (t + 1) >> 6;
      if (cn < 256) pollGE(&flagChunk, cn + 1);
    }
    if ((t & 63) == 32) pollGE(&flagOut, t - 64);
    const float gpre = chunkS[((t + 1) >> 6) & 1][((t + 1) & 63) * 64 + lane];

    float ghb[6];
#pragma unroll
    for (int l = 1; l < 6; ++l) ghb[l] = ghv[l] + bihR[l - 1];

    float gi0v = gnext;
    float ns = 0.f;
#pragma unroll
    for (int l = 0; l < 6; ++l) {
      const float gh_g = ghv[l];
      const float s = (l == 0) ? (gi0v + gh_g) : dot16i(WBih[l - 1], ns_sg, ghb[l]);
      const float sg = sig_n(s);                   // r at qg=0, z at qg=1
      const float smg = s - gh_g;                  // scaled i_n at qg=2
      const float sr = qbcast<0>(sg);
      const float sz = qbcast<1>(sg);
      const float a = sz * hv[l];                  // ready during tanh latency
      const float b = 1.f - sz;
      const float tq = tanh_p(fmaf(sr, gh_g, smg)); // n at qg=2
      ns = fmaf(tq, b, a);                         // valid at qg=2 lanes
      if (qg == 2) {
        nsS[wb][l * 16 + kk] = ns;
        if (l == 5) nsOut[(t & 255) * 16 + kk] = ns;
      }
      MEMBAR();
      // ns5 handoff is latency-critical: release gen5 + flag BEFORE readlanes
      if (l == 5 && lane == 0) { sigRel(&gen5[wb], t + 1); sigRel(&flagNs, t * 8 + 6); }
#pragma unroll
      for (int k = 0; k < 16; ++k) ns_sg[k] = rdlane(ns, 4 * k + 2);
      if (l < 5 && lane == 0) sigRel(&flagNs, t * 8 + l + 1);
    }
    hv5 = qbcast<2>(ns);                           // quad-uniform ns5, off-path
    gh5reg = dot16i(WB5, ns_sg, bhh5R);
    gnext = gpre;
  }
}

extern "C" void kernel_launch(void* const* d_in, const int* in_sizes, int n_in,
                              void* d_out, int out_size, void* d_ws, size_t ws_size,
                              hipStream_t stream) {
  const float* batch = (const float*)d_in[0];
  const float* h0    = (const float*)d_in[1];
  const float* Wih0  = (const float*)d_in[2];
  const float* Whh0  = (const float*)d_in[3];
  const float* bih0  = (const float*)d_in[4];
  const float* bhh0  = (const float*)d_in[5];
  const float* Wih   = (const float*)d_in[6];
  const float* Whh   = (const float*)d_in[7];
  const float* bih   = (const float*)d_in[8];
  const float* bhh   = (const float*)d_in[9];
  const float* Wa    = (const float*)d_in[10];
  const float* ba    = (const float*)d_in[11];
  const float* va    = (const float*)d_in[12];
  const float* fc1w  = (const float*)d_in[13];
  const float* fc1b  = (const float*)d_in[14];
  const float* fc2w  = (const float*)d_in[15];
  const float* fc2b  = (const float*)d_in[16];
  float* out = (float*)d_out;
  (void)in_sizes; (void)n_in; (void)out_size; (void)d_ws; (void)ws_size;

  gi0_gemm<<<TT / 64, 256, 0, stream>>>(batch, Wih0, bih0);
  fbrnn_scan<<<1, 512, 0, stream>>>(h0, Whh0, bhh0, Wih, Whh, bih, bhh,
                                    Wa, ba, va, fc1w, fc1b, fc2w, fc2b, out);
}

// Round 3
// 22108.636 us; speedup vs baseline: 1.3865x; 1.1303x over previous
//
#include <hip/hip_runtime.h>
#include <cstdint>
#include <cstddef>

// FBRNN: T=16384, F=2048, H=16, A=64, L=6, G=3H=48.
// gi0 GEMM precomputed in permuted layout [t][k*4+gate].
// Scan: 1 block x 512 threads, zero barriers in the step loop; LDS flag sync.
// R11: rows 0/1 combine tails computed IN the chain wave (ns5 already in
// registers -> no LDS round trip for the rows that gate layer 0/1). Rows 2-4
// stay on combine waves, consumed via speculative rec reads verified at the
// layer-1->2 boundary. bih folded into gh bases everywhere (ghb removed).
// Role map:
//   w0 = chain (layers 0-5 + row0/row1 j5-tails + finalize)
//   w4 = gi0 chunk streamer
//   w6 = row0 partial {j0,j1,j2} + fc head     -> partS[0]
//   w1 = row0 partial {j3,j4}                  -> partS[1]
//   w2 = row1 partial {j1,j2,j3}               -> partS[2]
//   w5 = row1 partial {j4} -> partS[3]; row4 {j4,j5}+fin -> recS[4]
//   w3 = row2 {j2,j3,j4,j5}+fin -> recS[2]
//   w7 = row3 {j3,j4,j5}+fin    -> recS[3]

#define TT 16384
#define FF 2048
#define HH 16
#define LL 6
#define GG 48
#define CHUNK 64
#define LOG2E 1.44269504088896340736f

__device__ float g_gi0p[(TT + CHUNK) * 64];

__device__ __forceinline__ float exp2_(float x) { return __builtin_amdgcn_exp2f(x); }
__device__ __forceinline__ float rcp_(float x) { return __builtin_amdgcn_rcpf(x); }
// sigmoid(x) with input pre-scaled s = -log2e*x
__device__ __forceinline__ float sig_n(float s) { return rcp_(1.f + exp2_(s)); }
// tanh(x) with input pre-scaled s = 2*log2e*x
__device__ __forceinline__ float tanh_p(float s) { return fmaf(-2.f, rcp_(exp2_(s) + 1.f), 1.f); }

#define MEMBAR() __asm__ __volatile__("" ::: "memory")

__device__ __forceinline__ float rdlane(float v, int l) {
  union { float f; int i; } a, b;
  a.f = v; b.i = __builtin_amdgcn_readlane(a.i, l); return b.f;
}
template <int CTRL>
__device__ __forceinline__ float dppf(float v) {
  union { float f; int i; } a, b;
  a.f = v; b.i = __builtin_amdgcn_mov_dpp(a.i, CTRL, 0xF, 0xF, true); return b.f;
}
template <int Q>
__device__ __forceinline__ float qbcast(float v) { return dppf<Q | (Q << 2) | (Q << 4) | (Q << 6)>(v); }

__device__ __forceinline__ float rowsum16(float v) {
  v += dppf<0xB1>(v);   // xor1
  v += dppf<0x4E>(v);   // xor2
  v += dppf<0x141>(v);  // row_half_mirror
  v += dppf<0x140>(v);  // row_mirror
  return v;
}
__device__ __forceinline__ float dot16r(const float (&w)[16], const float (&h)[16]) {
  float s0 = w[0] * h[0], s1 = w[1] * h[1], s2 = w[2] * h[2], s3 = w[3] * h[3];
#pragma unroll
  for (int k = 4; k < 16; k += 4) {
    s0 = fmaf(w[k], h[k], s0);       s1 = fmaf(w[k + 1], h[k + 1], s1);
    s2 = fmaf(w[k + 2], h[k + 2], s2); s3 = fmaf(w[k + 3], h[k + 3], s3);
  }
  return (s0 + s1) + (s2 + s3);
}
__device__ __forceinline__ float dot16i(const float (&w)[16], const float (&h)[16], float init) {
  float s0 = fmaf(w[0], h[0], init), s1 = w[1] * h[1], s2 = w[2] * h[2], s3 = w[3] * h[3];
#pragma unroll
  for (int k = 4; k < 16; k += 4) {
    s0 = fmaf(w[k], h[k], s0);       s1 = fmaf(w[k + 1], h[k + 1], s1);
    s2 = fmaf(w[k + 2], h[k + 2], s2); s3 = fmaf(w[k + 3], h[k + 3], s3);
  }
  return (s0 + s1) + (s2 + s3);
}

__device__ __forceinline__ int ldAcq(int* f) {
  return __hip_atomic_load(f, __ATOMIC_ACQUIRE, __HIP_MEMORY_SCOPE_WORKGROUP);
}
__device__ __forceinline__ void pollGE(int* f, int target) {
  while (ldAcq(f) < target) {}
}
__device__ __forceinline__ void waitFlag(int* f, int& cache, int need) {
  if (cache < need) { do { cache = ldAcq(f); } while (cache < need); }
}
// relaxed flag store: LDS ds ops are in-order per wave; MEMBAR() pins compile order.
__device__ __forceinline__ void sigRel(int* f, int v) {
  __hip_atomic_store(f, v, __ATOMIC_RELAXED, __HIP_MEMORY_SCOPE_WORKGROUP);
}

// one softmax term: energies over 64 attention lanes, P = Wh.nr per G-lane.
__device__ __forceinline__ void combBlock(const float4 A0, const float4 A1, const float4 A2,
                                          const float4 A3, float nsv,
                                          const float (&Wa)[16], float ba, float va,
                                          const float (&Wh)[16],
                                          float& S, float& ha, float& Pa) {
  float nr[16] = {A0.x, A0.y, A0.z, A0.w, A1.x, A1.y, A1.z, A1.w,
                  A2.x, A2.y, A2.z, A2.w, A3.x, A3.y, A3.z, A3.w};
  float u = dot16i(Wa, nr, ba);        // 2log2e * (ba + Wa.nr)
  float P = dot16r(Wh, nr);            // prescaled gh contribution (off u-path)
  float pe = va * tanh_p(u);           // log2e * va * tanh
  float r = rowsum16(pe);
  float e = (rdlane(r, 0) + rdlane(r, 16)) + (rdlane(r, 32) + rdlane(r, 48));
  float w = exp2_(e);                  // = exp(energy), va prescaled
  S += w; ha = fmaf(w, nsv, ha); Pa = fmaf(w, P, Pa);
}

// ---------------- Phase 1: gi0 GEMM (permuted + gate-prescaled output) ----------------
__global__ __launch_bounds__(256) void gi0_gemm(const float* __restrict__ X,
                                                const float* __restrict__ W,
                                                const float* __restrict__ bias) {
  __shared__ float xs[64][132];
  __shared__ float ws[48][132];
  const int tid = threadIdx.x;
  const int t0 = blockIdx.x * 64;
  const int tg = tid & 15;
  const int tt = tid >> 4;
  float acc[4][3];
#pragma unroll
  for (int u = 0; u < 4; ++u)
#pragma unroll
    for (int v = 0; v < 3; ++v) acc[u][v] = 0.f;

  for (int k0 = 0; k0 < FF; k0 += 128) {
#pragma unroll
    for (int i = 0; i < 32; ++i) {
      int e = tid + 256 * i; int r = e >> 7, c = e & 127;
      xs[r][c] = X[(size_t)(t0 + r) * FF + k0 + c];
    }
#pragma unroll
    for (int i = 0; i < 24; ++i) {
      int e = tid + 256 * i; int r = e >> 7, c = e & 127;
      ws[r][c] = W[(size_t)r * FF + k0 + c];
    }
    __syncthreads();
#pragma unroll 8
    for (int c = 0; c < 128; ++c) {
      float x0 = xs[tt][c], x1 = xs[tt + 16][c], x2 = xs[tt + 32][c], x3 = xs[tt + 48][c];
      float w0 = ws[tg][c], w1 = ws[tg + 16][c], w2 = ws[tg + 32][c];
      acc[0][0] += x0 * w0; acc[0][1] += x0 * w1; acc[0][2] += x0 * w2;
      acc[1][0] += x1 * w0; acc[1][1] += x1 * w1; acc[1][2] += x1 * w2;
      acc[2][0] += x2 * w0; acc[2][1] += x2 * w1; acc[2][2] += x2 * w2;
      acc[3][0] += x3 * w0; acc[3][1] += x3 * w1; acc[3][2] += x3 * w2;
    }
    __syncthreads();
  }
  const float gsc3[3] = {-LOG2E, -LOG2E, 2.f * LOG2E};  // r, z, n
#pragma unroll
  for (int u = 0; u < 4; ++u)
#pragma unroll
    for (int v = 0; v < 3; ++v)
      g_gi0p[(size_t)(t0 + tt + 16 * u) * 64 + tg * 4 + v] =
          (acc[u][v] + bias[tg + 16 * v]) * gsc3[v];
}

// ---------------- Phase 2: barrier-free sequential scan ----------------
__global__ __launch_bounds__(512, 1) void fbrnn_scan(
    const float* __restrict__ h0,
    const float* __restrict__ Whh0, const float* __restrict__ bhh0,
    const float* __restrict__ Wih, const float* __restrict__ Whh,
    const float* __restrict__ bih, const float* __restrict__ bhh,
    const float* __restrict__ Wa, const float* __restrict__ ba,
    const float* __restrict__ va,
    const float* __restrict__ fc1w, const float* __restrict__ fc1b,
    const float* __restrict__ fc2w, const float* __restrict__ fc2b,
    float* __restrict__ out) {
  __shared__ __align__(16) float nsS[2][LL * HH];     // ns, buf = t&1 (unscaled)
  __shared__ __align__(16) float4 recS[5 * 64];       // rows 2..4: {gh, h, gen, pad}
  __shared__ __align__(16) float4 partS[4 * 64];      // {S, ha, Pa, gen} partials
  __shared__ __align__(16) float nsOut[256 * HH];     // ns5 ring for fc (w6)
  __shared__ __align__(16) float chunkS[2][CHUNK * 64];
  __shared__ int flagNs;      // chain: t*8 + l + 1 after ns_l visible
  __shared__ int flagChunk;   // streamer: c+1 after chunk c staged
  __shared__ int flagOut;     // w6: t+1 after out[t] stored
  __shared__ int gen5[2];     // chain: t+1 after ns5 of step t stored in nsS[t&1]

  const int tid = threadIdx.x;
  const int wv = tid >> 6;
  const int lane = tid & 63;
  const int qg = lane & 3;
  const int kk = lane >> 2;
  const int gate = (qg < 3 ? qg : 2);
  const int G = gate * 16 + kk;               // gate-major row index
  const float gsc = (gate == 2) ? 2.f * LOG2E : -LOG2E;  // per-gate exp2 prescale

  const bool isChain = (wv == 0);
  const bool isStream = (wv == 4);
  const bool isFc = (wv == 6);
  // helper (partial) row and primary (tail) row per wave
  const int hRow = (wv == 6 || wv == 1) ? 0 : (wv == 2 || wv == 5) ? 1 : -1;
  const int pRow = (wv == 3) ? 2 : (wv == 7) ? 3 : (wv == 5) ? 4 : -1;
  const int pSlot = (wv == 6) ? 0 : (wv == 1) ? 1 : (wv == 2) ? 2 : (wv == 5) ? 3 : -1;

  // ---- per-role register weights (prescaled at load; bih folded into gh bases) ----
  float WBih[5][16];                    // chain: layers 1..5 input weights (x gsc)
  float WB5[16];  float bhh5R = 0.f;    // chain: Whh layer-5 row (+bih4, x gsc)
  float Wa0R[16], Wh0R[16], Wa1R[16], Wh1R[16];  // chain: rows 0/1 attn+hh
  float ba0R = 0.f, va0R = 0.f, bb0 = 0.f;
  float ba1R = 0.f, va1R = 0.f, bb1 = 0.f;
  float WaP[16], WhP[16];               // combine primary row
  float baP = 0.f, vaP = 0.f, bhhP = 0.f;
  float WaH[16], WhH[16];               // combine helper row
  float baH = 0.f, vaH = 0.f;
  float fc1R[16];                       // fc (unscaled)
  float fb1 = 0.f, fw2 = 0.f, fb2 = 0.f;

  if (isChain) {
#pragma unroll
    for (int l = 0; l < 5; ++l)
#pragma unroll
      for (int k = 0; k < 16; ++k) WBih[l][k] = Wih[((l * GG) + G) * 16 + k] * gsc;
#pragma unroll
    for (int k = 0; k < 16; ++k) WB5[k] = Whh[(4 * GG + G) * 16 + k] * gsc;
    bhh5R = (bhh[4 * GG + G] + bih[4 * GG + G]) * gsc;
    // row0 / row1 tail weights
#pragma unroll
    for (int k = 0; k < 16; ++k) {
      Wa0R[k] = Wa[(0 * 16 + k) * 64 + lane] * (2.f * LOG2E);
      Wa1R[k] = Wa[(1 * 16 + k) * 64 + lane] * (2.f * LOG2E);
      Wh0R[k] = Whh0[G * 16 + k] * gsc;
      Wh1R[k] = Whh[(0 * GG + G) * 16 + k] * gsc;
    }
    ba0R = ba[0 * 64 + lane] * (2.f * LOG2E); va0R = va[0 * 64 + lane] * LOG2E;
    ba1R = ba[1 * 64 + lane] * (2.f * LOG2E); va1R = va[1 * 64 + lane] * LOG2E;
    bb0 = bhh0[G] * gsc;
    bb1 = (bhh[0 * GG + G] + bih[0 * GG + G]) * gsc;
  }
  if (pRow >= 0) {
#pragma unroll
    for (int k = 0; k < 16; ++k) WaP[k] = Wa[(pRow * 16 + k) * 64 + lane] * (2.f * LOG2E);
    baP = ba[pRow * 64 + lane] * (2.f * LOG2E);
    vaP = va[pRow * 64 + lane] * LOG2E;
    const float* ws = Whh + ((pRow - 1) * GG + G) * 16;
#pragma unroll
    for (int k = 0; k < 16; ++k) WhP[k] = ws[k] * gsc;
    bhhP = (bhh[(pRow - 1) * GG + G] + bih[(pRow - 1) * GG + G]) * gsc;  // +bih fold
  }
  if (hRow >= 0) {
#pragma unroll
    for (int k = 0; k < 16; ++k) WaH[k] = Wa[(hRow * 16 + k) * 64 + lane] * (2.f * LOG2E);
    baH = ba[hRow * 64 + lane] * (2.f * LOG2E);
    vaH = va[hRow * 64 + lane] * LOG2E;
    const float* ws = (hRow == 0) ? (Whh0 + G * 16) : (Whh + ((hRow - 1) * GG + G) * 16);
#pragma unroll
    for (int k = 0; k < 16; ++k) WhH[k] = ws[k] * gsc;
  }
  if (isFc) {
    const int m = lane & 31;
#pragma unroll
    for (int k = 0; k < 16; ++k) fc1R[k] = fc1w[m * 16 + k];
    fb1 = fc1b[m]; fw2 = fc2w[m]; fb2 = fc2b[0];
  }

  if (tid == 0) { flagNs = 0; flagChunk = 1; flagOut = 0; gen5[0] = 0; gen5[1] = 0; }

  // chain state registers
  float hv5 = 0.f, gh5reg = 0.f;
  float gh0n = 0.f, hv0n = 0.f, gh1n = 0.f, hv1n = 0.f;
  if (isChain) {
    float hr[16];
#pragma unroll
    for (int k = 0; k < 16; ++k) hr[k] = h0[5 * 16 + k];
    hv5 = h0[5 * 16 + kk];
    gh5reg = dot16i(WB5, hr, bhh5R);
#pragma unroll
    for (int k = 0; k < 16; ++k) hr[k] = h0[0 * 16 + k];
    hv0n = h0[0 * 16 + kk];
    gh0n = dot16i(Wh0R, hr, bb0);
#pragma unroll
    for (int k = 0; k < 16; ++k) hr[k] = h0[1 * 16 + k];
    hv1n = h0[1 * 16 + kk];
    gh1n = dot16i(Wh1R, hr, bb1);
  } else if (pRow >= 0) {
    // init rec row pRow from h0, gen = 0
    float hr[16];
#pragma unroll
    for (int k = 0; k < 16; ++k) hr[k] = h0[pRow * 16 + k];
    float4 rr;
    rr.x = dot16i(WhP, hr, bhhP);
    rr.y = h0[pRow * 16 + kk];
    rr.z = __int_as_float(0);
    rr.w = 0.f;
    recS[pRow * 64 + lane] = rr;
  }
  if (isStream) {
    const float4* src = (const float4*)g_gi0p;
    float4* dst = (float4*)(&chunkS[0][0]);
#pragma unroll
    for (int q = 0; q < 16; ++q) dst[q * 64 + lane] = src[q * 64 + lane];
  }
  if (pSlot >= 0) partS[pSlot * 64 + lane] = make_float4(0.f, 0.f, 0.f, __int_as_float(0));
  __syncthreads();  // the only barrier

// early combine block: wait flag, read nsS row J, accumulate one term
#define EBLOCK(J, WaX, baX, vaX, WhX, Sx, hax, Pax) do {                          \
    waitFlag(&flagNs, fcache, t * 8 + (J) + 1);                                   \
    const float4* np_ = (const float4*)&nsS[nb][(J) * 16];                        \
    float4 A0_ = np_[0], A1_ = np_[1], A2_ = np_[2], A3_ = np_[3];                \
    float nsv_ = nsS[nb][(J) * 16 + kk];                                          \
    combBlock(A0_, A1_, A2_, A3_, nsv_, WaX, baX, vaX, WhX, Sx, hax, Pax);        \
  } while (0)

// j=5 tail: gen5 poll (data read in-iteration), accumulate, finalize, write rec
#define TAILFIN(ROW, Sv, hav, Pav) do {                                           \
    float4 A0, A1, A2, A3; float nsv5;                                            \
    for (;;) {                                                                    \
      int g5 = ldAcq(&gen5[nb]);                                                  \
      MEMBAR();                                                                   \
      const float4* np = (const float4*)&nsS[nb][5 * 16];                         \
      A0 = np[0]; A1 = np[1]; A2 = np[2]; A3 = np[3];                             \
      nsv5 = nsS[nb][5 * 16 + kk];                                                \
      MEMBAR();                                                                   \
      if (g5 >= tgt) break;                                                       \
    }                                                                             \
    combBlock(A0, A1, A2, A3, nsv5, WaP, baP, vaP, WhP, Sv, hav, Pav);            \
    const float inv_ = rcp_(Sv);                                                  \
    float4 rr_; rr_.x = fmaf(Pav, inv_, bhhP); rr_.y = hav * inv_;                \
    rr_.z = __int_as_float(tgt); rr_.w = 0.f;                                     \
    recS[(ROW) * 64 + lane] = rr_;                                                \
  } while (0)

  // ================= streamer (w4) =================
  if (isStream) {
#pragma unroll 1
    for (int c = 1; c < 256; ++c) {
      if (c >= 2) pollGE(&flagNs, ((c - 1) * 64 - 1) * 8 + 1);
      const float4* src = (const float4*)(g_gi0p + ((size_t)c << 12));
      float4* dst = (float4*)(&chunkS[c & 1][0]);
#pragma unroll
      for (int q = 0; q < 16; ++q) dst[q * 64 + lane] = src[q * 64 + lane];
      MEMBAR();
      sigRel(&flagChunk, c + 1);
    }
    return;
  }

  // ================= w6: row0 partial {j0,j1,j2} + fc head =================
  if (isFc) {
    int fcache = 0;
#pragma unroll 1
    for (int t = 0; t < TT; ++t) {
      const int nb = t & 1;
      float Sh = 0.f, hah = 0.f, Pah = 0.f;
      EBLOCK(0, WaH, baH, vaH, WhH, Sh, hah, Pah);
      EBLOCK(1, WaH, baH, vaH, WhH, Sh, hah, Pah);
      EBLOCK(2, WaH, baH, vaH, WhH, Sh, hah, Pah);
      partS[0 * 64 + lane] = make_float4(Sh, hah, Pah, __int_as_float(t + 1));
      // fc tail
      waitFlag(&flagNs, fcache, t * 8 + 6);
      const float4* np = (const float4*)(nsOut + (t & 255) * 16);
      float4 a0 = np[0], a1 = np[1], a2 = np[2], a3 = np[3];
      float nr[16] = {a0.x, a0.y, a0.z, a0.w, a1.x, a1.y, a1.z, a1.w,
                      a2.x, a2.y, a2.z, a2.w, a3.x, a3.y, a3.z, a3.w};
      float y = dot16i(fc1R, nr, fb1);
      float p = rowsum16(y * fw2);
      float o = rdlane(p, 0) + rdlane(p, 16) + fb2;
      if (lane == 0) out[t] = o;
      MEMBAR();
      sigRel(&flagOut, t + 1);
    }
    return;
  }

  // ================= combine / partial waves =================
  if (!isChain) {
    int fcache = 0;
    if (wv == 1) {         // row0 partial {j3,j4}
#pragma unroll 1
      for (int t = 0; t < TT; ++t) {
        const int nb = t & 1;
        float Sh = 0.f, hah = 0.f, Pah = 0.f;
        EBLOCK(3, WaH, baH, vaH, WhH, Sh, hah, Pah);
        EBLOCK(4, WaH, baH, vaH, WhH, Sh, hah, Pah);
        partS[1 * 64 + lane] = make_float4(Sh, hah, Pah, __int_as_float(t + 1));
      }
    } else if (wv == 2) {  // row1 partial {j1,j2,j3}
#pragma unroll 1
      for (int t = 0; t < TT; ++t) {
        const int nb = t & 1;
        float Sh = 0.f, hah = 0.f, Pah = 0.f;
        EBLOCK(1, WaH, baH, vaH, WhH, Sh, hah, Pah);
        EBLOCK(2, WaH, baH, vaH, WhH, Sh, hah, Pah);
        EBLOCK(3, WaH, baH, vaH, WhH, Sh, hah, Pah);
        partS[2 * 64 + lane] = make_float4(Sh, hah, Pah, __int_as_float(t + 1));
      }
    } else if (wv == 5) {  // row1 partial {j4}; row4 {j4,j5}+fin
#pragma unroll 1
      for (int t = 0; t < TT; ++t) {
        const int nb = t & 1;
        const int tgt = t + 1;
        float Sh = 0.f, hah = 0.f, Pah = 0.f;
        EBLOCK(4, WaH, baH, vaH, WhH, Sh, hah, Pah);
        partS[3 * 64 + lane] = make_float4(Sh, hah, Pah, __int_as_float(tgt));
        float S = 0.f, ha = 0.f, Pa = 0.f;
        EBLOCK(4, WaP, baP, vaP, WhP, S, ha, Pa);
        TAILFIN(4, S, ha, Pa);
      }
    } else if (wv == 3) {  // row2 {j2,j3,j4,j5}+fin
#pragma unroll 1
      for (int t = 0; t < TT; ++t) {
        const int nb = t & 1;
        const int tgt = t + 1;
        float S = 0.f, ha = 0.f, Pa = 0.f;
        EBLOCK(2, WaP, baP, vaP, WhP, S, ha, Pa);
        EBLOCK(3, WaP, baP, vaP, WhP, S, ha, Pa);
        EBLOCK(4, WaP, baP, vaP, WhP, S, ha, Pa);
        TAILFIN(2, S, ha, Pa);
      }
    } else {               // wv == 7: row3 {j3,j4,j5}+fin
#pragma unroll 1
      for (int t = 0; t < TT; ++t) {
        const int nb = t & 1;
        const int tgt = t + 1;
        float S = 0.f, ha = 0.f, Pa = 0.f;
        EBLOCK(3, WaP, baP, vaP, WhP, S, ha, Pa);
        EBLOCK(4, WaP, baP, vaP, WhP, S, ha, Pa);
        TAILFIN(3, S, ha, Pa);
      }
    }
    return;
  }

  // ================= GRU chain (w0) =================
  float gnext = chunkS[0][lane];
  float ns_sg[16];
#pragma unroll 1
  for (int t = 0; t < TT; ++t) {
    const int wb = t & 1;        // ns buf this step

    float ghv[6], hv[6];
    ghv[0] = gh0n; hv[0] = hv0n;
    ghv[1] = gh1n; hv[1] = hv1n;
    ghv[5] = gh5reg; hv[5] = hv5;
    float4 r2, r3, r4;
    float gpre = 0.f;
    float gi0v = gnext;
    float ns = 0.f;
#pragma unroll
    for (int l = 0; l < 6; ++l) {
      if (l == 2) {
        // rec rows 2-4: speculative reads (issued in l==0 tail) verified here
        if (!((__float_as_int(r2.z) >= t) & (__float_as_int(r3.z) >= t) &
              (__float_as_int(r4.z) >= t))) {
          do {
            MEMBAR();
            r2 = recS[2 * 64 + lane]; r3 = recS[3 * 64 + lane]; r4 = recS[4 * 64 + lane];
            MEMBAR();
          } while (!((__float_as_int(r2.z) >= t) & (__float_as_int(r3.z) >= t) &
                     (__float_as_int(r4.z) >= t)));
        }
        ghv[2] = r2.x; hv[2] = r2.y;
        ghv[3] = r3.x; hv[3] = r3.y;
        ghv[4] = r4.x; hv[4] = r4.y;
      }
      const float gh_g = ghv[l];
      const float s = (l == 0) ? (gi0v + gh_g) : dot16i(WBih[l - 1], ns_sg, gh_g);
      const float sg = sig_n(s);                    // r at qg=0, z at qg=1
      const float smg = s - gh_g;                   // scaled i_n at qg=2
      const float sr = qbcast<0>(sg);
      const float sz = qbcast<1>(sg);
      const float a = sz * hv[l];                   // ready during tanh latency
      const float b = 1.f - sz;
      const float tq = tanh_p(fmaf(sr, gh_g, smg)); // n at qg=2
      ns = fmaf(tq, b, a);                          // valid at qg=2 lanes
      if (qg == 2) {
        nsS[wb][l * 16 + kk] = ns;
        if (l == 5) nsOut[(t & 255) * 16 + kk] = ns;
      }
      MEMBAR();
      // ns5 handoff is latency-critical: release gen5 + flag BEFORE readlanes
      if (l == 5 && lane == 0) { sigRel(&gen5[wb], t + 1); sigRel(&flagNs, t * 8 + 6); }
#pragma unroll
      for (int k = 0; k < 16; ++k) ns_sg[k] = rdlane(ns, 4 * k + 2);
      if (l < 5 && lane == 0) sigRel(&flagNs, t * 8 + l + 1);
      if (l == 0) {
        // slack region: housekeeping + prefetch + rec spec reads
        if ((t & 63) == 63) {
          const int cn = (t + 1) >> 6;
          if (cn < 256) pollGE(&flagChunk, cn + 1);
        }
        if ((t & 63) == 32) pollGE(&flagOut, t - 64);
        gpre = chunkS[((t + 1) >> 6) & 1][((t + 1) & 63) * 64 + lane];
        MEMBAR();
        r2 = recS[2 * 64 + lane]; r3 = recS[3 * 64 + lane]; r4 = recS[4 * 64 + lane];
        MEMBAR();
      }
    }
    // ---- post-layer-5: next-step state (row 5 + in-chain row0/row1 tails) ----
    const float hv5n = qbcast<2>(ns);               // ns5[kk] per lane
    gh5reg = dot16i(WB5, ns_sg, bhh5R);
    // row0/row1 j=5 energies + P (ns_sg already in registers: no LDS hop)
    float u0 = dot16i(Wa0R, ns_sg, ba0R);
    float u1 = dot16i(Wa1R, ns_sg, ba1R);
    float P0 = dot16r(Wh0R, ns_sg);
    float P1 = dot16r(Wh1R, ns_sg);
    // speculative partial reads (arrive ~ns4+400, i.e. before they're needed)
    MEMBAR();
    float4 p0a = partS[0 * 64 + lane], p0b = partS[1 * 64 + lane];
    float4 p1a = partS[2 * 64 + lane], p1b = partS[3 * 64 + lane];
    MEMBAR();
    float pe0 = va0R * tanh_p(u0);
    float pe1 = va1R * tanh_p(u1);
    float rs0 = rowsum16(pe0);
    float rs1 = rowsum16(pe1);
    float e0 = (rdlane(rs0, 0) + rdlane(rs0, 16)) + (rdlane(rs0, 32) + rdlane(rs0, 48));
    float e1 = (rdlane(rs1, 0) + rdlane(rs1, 16)) + (rdlane(rs1, 32) + rdlane(rs1, 48));
    float wj0 = exp2_(e0), wj1 = exp2_(e1);
    const int tp = t + 1;
    if (!((__float_as_int(p0a.w) >= tp) & (__float_as_int(p0b.w) >= tp) &
          (__float_as_int(p1a.w) >= tp) & (__float_as_int(p1b.w) >= tp))) {
      do {
        MEMBAR();
        p0a = partS[0 * 64 + lane]; p0b = partS[1 * 64 + lane];
        p1a = partS[2 * 64 + lane]; p1b = partS[3 * 64 + lane];
        MEMBAR();
      } while (!((__float_as_int(p0a.w) >= tp) & (__float_as_int(p0b.w) >= tp) &
                 (__float_as_int(p1a.w) >= tp) & (__float_as_int(p1b.w) >= tp)));
    }
    float S0 = p0a.x + p0b.x + wj0;
    float hT0 = p0a.y + p0b.y + wj0 * hv5n;
    float PT0 = p0a.z + p0b.z + wj0 * P0;
    float S1 = p1a.x + p1b.x + wj1;
    float hT1 = p1a.y + p1b.y + wj1 * hv5n;
    float PT1 = p1a.z + p1b.z + wj1 * P1;
    const float inv0 = rcp_(S0);
    const float inv1 = rcp_(S1);
    gh0n = fmaf(PT0, inv0, bb0); hv0n = hT0 * inv0;
    gh1n = fmaf(PT1, inv1, bb1); hv1n = hT1 * inv1;
    hv5 = hv5n;
    gnext = gpre;
  }
}

extern "C" void kernel_launch(void* const* d_in, const int* in_sizes, int n_in,
                              void* d_out, int out_size, void* d_ws, size_t ws_size,
                              hipStream_t stream) {
  const float* batch = (const float*)d_in[0];
  const float* h0    = (const float*)d_in[1];
  const float* Wih0  = (const float*)d_in[2];
  const float* Whh0  = (const float*)d_in[3];
  const float* bih0  = (const float*)d_in[4];
  const float* bhh0  = (const float*)d_in[5];
  const float* Wih   = (const float*)d_in[6];
  const float* Whh   = (const float*)d_in[7];
  const float* bih   = (const float*)d_in[8];
  const float* bhh   = (const float*)d_in[9];
  const float* Wa    = (const float*)d_in[10];
  const float* ba    = (const float*)d_in[11];
  const float* va    = (const float*)d_in[12];
  const float* fc1w  = (const float*)d_in[13];
  const float* fc1b  = (const float*)d_in[14];
  const float* fc2w  = (const float*)d_in[15];
  const float* fc2b  = (const float*)d_in[16];
  float* out = (float*)d_out;
  (void)in_sizes; (void)n_in; (void)out_size; (void)d_ws; (void)ws_size;

  gi0_gemm<<<TT / 64, 256, 0, stream>>>(batch, Wih0, bih0);
  fbrnn_scan<<<1, 512, 0, stream>>>(h0, Whh0, bhh0, Wih, Whh, bih, bhh,
                                    Wa, ba, va, fc1w, fc1b, fc2w, fc2b, out);
}